// Round 6
// baseline (165.232 us; speedup 1.0000x reference)
//
#include <hip/hip_runtime.h>
#include <math.h>

constexpr int D = 64;
constexpr int H = 4;
constexpr int EB = 8192;   // edges per binning block
constexpr int PADC = 46;   // cols inlined in per-node record (48 words total)

// ---------------------------------------------------------------------------
// R25: aggregate is random-gather bound (R24: FETCH 105MB / 41us = 2.56TB/s
// effective; VALU cuts didn't move it).  Serial chain was 3 dependent VMEM
// hops: off[n] -> sc[off0+l] -> KVP gathers.  bucket_sort now emits a padded
// per-node record pvec[n*48] = {deg, off0, col0..col45} (192B); aggregate
// does ONE coalesced record load (lanes 0-47), shfl's cols from registers,
// then gathers: 3 hops -> 2.  deg>46 falls back to sc (still written).
// off[] eliminated.  Harness fillBuffer (~42us re-poison) is fixed overhead.
// R24: step-exact quad/pair/single ladders; qkv 4x tile amortization.
// R23: consolidated 6-dispatch sort, shfl-fed gathers.  R22: contention-
// free 2-level counting sort.  R20: lane=dim-quad d=l&15, slot es=l>>4.
// Layouts (verified learn_hip m89/m120): A[m=lane&15][k=(lane>>4)*8+j],
// B[k=(lane>>4)*8+j][n=lane&15], C/D col=lane&15 row=(lane>>4)*4+reg.
// ---------------------------------------------------------------------------

typedef __attribute__((ext_vector_type(8))) short bf16x8;
typedef __attribute__((ext_vector_type(4))) float f32x4;

__device__ __forceinline__ unsigned short f32_to_bf16(float f) {
    const unsigned int u = __float_as_uint(f);
    return (unsigned short)((u + 0x7FFFu + ((u >> 16) & 1u)) >> 16);  // RNE
}
__device__ __forceinline__ float bf16_to_f32(unsigned short h) {
    return __uint_as_float(((unsigned int)h) << 16);
}
__device__ __forceinline__ float bf16lo_f32(unsigned int w) {   // bits 0-15
    return __uint_as_float(w << 16);
}
__device__ __forceinline__ float bf16hi_f32(unsigned int w) {   // bits 16-31
    return __uint_as_float(w & 0xFFFF0000u);
}

// ---------------------------------------------------------------------------
// Kernel 0: pre-split W into hi/lo MFMA B-fragment order with PERMUTED column
// map: fragment (mt, ct, ks, lane l, j) <- W_mt[ks*32+(l>>4)*8+j][4*(l&15)+ct]
// so MFMA acc[mt][ct] at lane m holds ORIGINAL output col 4m+ct.
// ---------------------------------------------------------------------------
__global__ __launch_bounds__(256) void prep_w_kernel(
    const float* __restrict__ Wq, const float* __restrict__ Wk,
    const float* __restrict__ Wv,
    unsigned short* __restrict__ WfH, unsigned short* __restrict__ WfL) {
    const float* W[3] = {Wq, Wk, Wv};
    for (int idx = blockIdx.x * 256 + threadIdx.x; idx < 3 * 4 * 2 * 64 * 8;
         idx += gridDim.x * 256) {
        const int j  = idx & 7;
        const int l  = (idx >> 3) & 63;
        const int ks = (idx >> 9) & 1;
        const int ct = (idx >> 10) & 3;
        const int mt = idx >> 12;
        const int krow = ks * 32 + (l >> 4) * 8 + j;
        const int col  = 4 * (l & 15) + ct;          // permuted column map
        const float w  = W[mt][krow * 64 + col];
        const unsigned short h = f32_to_bf16(w);
        WfH[idx] = h;
        WfL[idx] = f32_to_bf16(w - bf16_to_f32(h));
    }
}

// ---------------------------------------------------------------------------
// Kernel 1 (fused): blocks [0,HB) = bin_hist (LDS-only bucket histogram);
// blocks [HB,HB+QB) = QKV projection, 256 nodes/block (4 tiles per wave).
// ---------------------------------------------------------------------------
__global__ __launch_bounds__(256) void fused_qkv_hist_kernel(
    const float* __restrict__ emb,
    const unsigned short* __restrict__ WfH,
    const unsigned short* __restrict__ WfL,
    int N, float* __restrict__ Q, unsigned int* __restrict__ KVP,
    const int* __restrict__ rows, int* __restrict__ hist2d,
    int E, int NB, int HB) {
    __shared__ unsigned short sH[12288];   // 24 KB
    __shared__ unsigned short sL[12288];   // 24 KB
    __shared__ int h[512];                 // 2 KB (bin_hist part)
    const int tid = threadIdx.x;

    if ((int)blockIdx.x < HB) {
        // ---- bin_hist: per-block LDS histogram over 256-node buckets ----
        const int blk = blockIdx.x;
        for (int b = tid; b < NB; b += 256) h[b] = 0;
        __syncthreads();
        const int e0 = blk * EB;
        const int e1 = min(E, e0 + EB);
        for (int i = e0 + tid; i < e1; i += 256)
            atomicAdd(&h[rows[i] >> 8], 1);            // LDS, contention ~21
        __syncthreads();
        for (int b = tid; b < NB; b += 256) hist2d[blk * NB + b] = h[b];
        return;
    }

    // ---- qkv ----
    const int bx = blockIdx.x - HB;
    {
        const uint4* gh = (const uint4*)WfH;
        const uint4* gl = (const uint4*)WfL;
        uint4* shh = (uint4*)sH;
        uint4* sll = (uint4*)sL;
        for (int k = tid; k < 1536; k += 256) {
            shh[k] = gh[k];
            sll[k] = gl[k];
        }
    }
    __syncthreads();

    const int wv = tid >> 6;
    const int l  = tid & 63;
    const int qd = l >> 4;              // quad 0..3
    const int m  = l & 15;

    for (int tile = 0; tile < 4; ++tile) {
        const int n0 = bx * 256 + tile * 64 + wv * 16;
        if (n0 >= N) break;

        // A fragments, split hi/lo: k = ks*32 + qd*8 + j
        bf16x8 aH[2], aL[2];
        {
            int node = n0 + m;
            if (node >= N) node = N - 1;
            const float4* ep = (const float4*)(emb + (size_t)node * 64);
#pragma unroll
            for (int ks = 0; ks < 2; ++ks) {
                const float4 a0 = ep[ks * 8 + qd * 2 + 0];
                const float4 a1 = ep[ks * 8 + qd * 2 + 1];
                const float f[8] = {a0.x, a0.y, a0.z, a0.w,
                                    a1.x, a1.y, a1.z, a1.w};
                bf16x8 fh, fl;
#pragma unroll
                for (int j = 0; j < 8; ++j) {
                    const unsigned short hh = f32_to_bf16(f[j]);
                    fh[j] = (short)hh;
                    fl[j] = (short)f32_to_bf16(f[j] - bf16_to_f32(hh));
                }
                aH[ks] = fh;
                aL[ks] = fl;
            }
        }

        f32x4 acc[3][4];
#pragma unroll
        for (int mt = 0; mt < 3; ++mt)
#pragma unroll
            for (int ct = 0; ct < 4; ++ct)
                acc[mt][ct] = (f32x4){0.f, 0.f, 0.f, 0.f};

#pragma unroll
        for (int mt = 0; mt < 3; ++mt) {
#pragma unroll
            for (int ct = 0; ct < 4; ++ct) {
#pragma unroll
                for (int ks = 0; ks < 2; ++ks) {
                    const int fi = (((mt * 4 + ct) * 2 + ks) * 64 + l) * 8;
                    bf16x8 bh = *(const bf16x8*)&sH[fi];
                    bf16x8 bl = *(const bf16x8*)&sL[fi];
                    acc[mt][ct] = __builtin_amdgcn_mfma_f32_16x16x32_bf16(
                        aH[ks], bh, acc[mt][ct], 0, 0, 0);
                    acc[mt][ct] = __builtin_amdgcn_mfma_f32_16x16x32_bf16(
                        aH[ks], bl, acc[mt][ct], 0, 0, 0);
                    acc[mt][ct] = __builtin_amdgcn_mfma_f32_16x16x32_bf16(
                        aL[ks], bh, acc[mt][ct], 0, 0, 0);
                }
            }
        }

        // Epilogue: lane holds original cols 4m+ct (ct=0..3), row = qd*4+r.
#pragma unroll
        for (int r = 0; r < 4; ++r) {
            const int node = n0 + qd * 4 + r;
            if (node < N) {
                float4 oq;
                oq.x = acc[0][0][r]; oq.y = acc[0][1][r];
                oq.z = acc[0][2][r]; oq.w = acc[0][3][r];
                *(float4*)(Q + (size_t)node * 64 + 4 * m) = oq;

                uint4 kv;   // {kpack(4m,4m+1), vpack, kpack(4m+2,4m+3), vpack}
                kv.x = (unsigned int)f32_to_bf16(acc[1][0][r]) |
                       ((unsigned int)f32_to_bf16(acc[1][1][r]) << 16);
                kv.y = (unsigned int)f32_to_bf16(acc[2][0][r]) |
                       ((unsigned int)f32_to_bf16(acc[2][1][r]) << 16);
                kv.z = (unsigned int)f32_to_bf16(acc[1][2][r]) |
                       ((unsigned int)f32_to_bf16(acc[1][3][r]) << 16);
                kv.w = (unsigned int)f32_to_bf16(acc[2][2][r]) |
                       ((unsigned int)f32_to_bf16(acc[2][3][r]) << 16);
                *(uint4*)(KVP + (size_t)node * 64 + 4 * m) = kv;
            }
        }
    }
}

// Per-bucket exclusive scan over binning blocks (column b of hist2d).
// base2d[blk][b] = prefix within bucket (WITHOUT bucket base); btot[b]=total.
__global__ __launch_bounds__(256) void scan2d_kernel(
    const int* __restrict__ hist2d, int* __restrict__ base2d,
    int* __restrict__ btot, int NBLK, int NB) {
    __shared__ int s[256];
    const int b   = blockIdx.x;
    const int tid = threadIdx.x;
    const int x = (tid < NBLK) ? hist2d[tid * NB + b] : 0;
    s[tid] = x;
    __syncthreads();
    for (int o = 1; o < 256; o <<= 1) {
        int v = 0;
        if (tid >= o) v = s[tid - o];
        __syncthreads();
        if (tid >= o) s[tid] += v;
        __syncthreads();
    }
    if (tid < NBLK) base2d[tid * NB + b] = s[tid] - x;
    if (tid == 255) btot[b] = s[255];
}

// Exclusive scan of the NB bucket totals (1 block, chunked).
__global__ __launch_bounds__(256) void bscan_kernel(
    const int* __restrict__ btot, int* __restrict__ bbase, int NB) {
    __shared__ int s[256];
    __shared__ int carry;
    const int tid = threadIdx.x;
    if (tid == 0) carry = 0;
    __syncthreads();
    for (int base = 0; base < NB; base += 256) {
        const int i = base + tid;
        const int x = (i < NB) ? btot[i] : 0;
        s[tid] = x;
        __syncthreads();
        for (int o = 1; o < 256; o <<= 1) {
            int v = 0;
            if (tid >= o) v = s[tid - o];
            __syncthreads();
            if (tid >= o) s[tid] += v;
            __syncthreads();
        }
        if (i < NB) bbase[i] = carry + s[tid] - x;
        __syncthreads();
        if (tid == 255) carry += s[255];
        __syncthreads();
    }
}

// Phase A: each block places its edges into PRIVATE per-bucket sub-ranges
// via LDS cursors -> zero global atomics, contiguous write runs.
__global__ __launch_bounds__(256) void scatter2d_kernel(
    const int* __restrict__ rows, const int* __restrict__ cols,
    const int* __restrict__ base2d, const int* __restrict__ bbase,
    unsigned int* __restrict__ tmp, int E, int NB) {
    __shared__ int lcur[512];
    const int tid = threadIdx.x;
    const int blk = blockIdx.x;
    for (int b = tid; b < NB; b += 256)
        lcur[b] = bbase[b] + base2d[blk * NB + b];
    __syncthreads();
    const int e0 = blk * EB;
    const int e1 = min(E, e0 + EB);
    for (int i = e0 + tid; i < e1; i += 256) {
        const int r = rows[i];
        const int c = cols[i];
        const int p = atomicAdd(&lcur[r >> 8], 1);   // LDS atomic
        tmp[p] = ((unsigned int)(r & 255) << 24) | (unsigned int)c;
    }
}

// Phase B: block per bucket.  LDS histogram -> per-node placement -> emits
// (a) coalesced sc (fallback path) and (b) padded per-node records
// pvec[n*48] = {deg, off0, col0..col45} consumed by aggregate.
__global__ __launch_bounds__(256) void bucket_sort_kernel(
    const unsigned int* __restrict__ tmp, const int* __restrict__ bbase,
    const int* __restrict__ btot, int* __restrict__ pvec,
    int* __restrict__ sc, int N, int E, int NB) {
    __shared__ unsigned int ebuf[4096];   // 16 KB
    __shared__ int sbuf[4096];            // 16 KB
    __shared__ int lhist[256];
    __shared__ int s[256];
    __shared__ int lcur[256];
    const int b     = blockIdx.x;
    const int tid   = threadIdx.x;
    const int n0    = b * 256;
    const int gbase = bbase[b];
    const int cnt_b = btot[b];

    lhist[tid] = 0;
    __syncthreads();

    if (cnt_b <= 4096) {
        for (int i = tid; i < cnt_b; i += 256) {
            const unsigned int w = tmp[gbase + i];
            ebuf[i] = w;
            atomicAdd(&lhist[w >> 24], 1);            // LDS, contention ~8
        }
        __syncthreads();
        // exclusive scan of lhist
        const int x = lhist[tid];
        s[tid] = x;
        __syncthreads();
        for (int o = 1; o < 256; o <<= 1) {
            int v = 0;
            if (tid >= o) v = s[tid - o];
            __syncthreads();
            if (tid >= o) s[tid] += v;
            __syncthreads();
        }
        const int excl = s[tid] - x;
        lcur[tid] = excl;
        __syncthreads();
        for (int i = tid; i < cnt_b; i += 256) {
            const unsigned int w = ebuf[i];
            const int p = atomicAdd(&lcur[w >> 24], 1);
            sbuf[p] = (int)(w & 0x00FFFFFFu);
        }
        __syncthreads();
        for (int i = tid; i < cnt_b; i += 256) sc[gbase + i] = sbuf[i];
        // padded record for this thread's node
        const int node = n0 + tid;
        if (node < N) {
            int* rec = pvec + (size_t)node * 48;
            rec[0] = x;
            rec[1] = gbase + excl;
            const int m = min(x, PADC);
            for (int j = 0; j < m; ++j) rec[2 + j] = sbuf[excl + j];
        }
    } else {
        // Fallback (never expected at E/N=8): direct global placement.
        for (int i = tid; i < cnt_b; i += 256)
            atomicAdd(&lhist[tmp[gbase + i] >> 24], 1);
        __syncthreads();
        const int x = lhist[tid];
        s[tid] = x;
        __syncthreads();
        for (int o = 1; o < 256; o <<= 1) {
            int v = 0;
            if (tid >= o) v = s[tid - o];
            __syncthreads();
            if (tid >= o) s[tid] += v;
            __syncthreads();
        }
        const int excl = s[tid] - x;
        lcur[tid] = excl;
        __syncthreads();
        for (int i = tid; i < cnt_b; i += 256) {
            const unsigned int w = tmp[gbase + i];
            const int p = atomicAdd(&lcur[w >> 24], 1);
            sc[gbase + p] = (int)(w & 0x00FFFFFFu);
        }
        __syncthreads();
        const int node = n0 + tid;
        if (node < N) {
            int* rec = pvec + (size_t)node * 48;
            rec[0] = x;
            rec[1] = gbase + excl;
            const int m = min(x, PADC);
            for (int j = 0; j < m; ++j) rec[2 + j] = sc[gbase + excl + j];
        }
    }
}

// ---------------------------------------------------------------------------
// Kernel 2: atomic-free aggregation.  lane l: d=l&15 (dim quad, one uint4 of
// KVP), es=l>>4 (edge slot).  ONE coalesced record load (lanes 0-47) gives
// deg/off0/cols in registers; cols come via __shfl -> serial chain is
// record -> KVP (2 hops).  Step-exact quad/pair/single ladders; deg>PADC
// tail falls back to sc reads.
// ---------------------------------------------------------------------------
__device__ __forceinline__ void agg_step(const uint4 kv, const float4 q4,
                                         bool ok, float& aN, float& a0,
                                         float& a1, float& a2, float& a3) {
    float pp = q4.x * bf16lo_f32(kv.x);
    pp = fmaf(q4.y, bf16hi_f32(kv.x), pp);
    pp = fmaf(q4.z, bf16lo_f32(kv.z), pp);
    pp = fmaf(q4.w, bf16hi_f32(kv.z), pp);
    pp += __shfl_xor(pp, 1);
    pp += __shfl_xor(pp, 2);
    float e = __expf(fminf(fmaxf(pp, -10.f), 10.f));
    e = ok ? e : 0.f;
    aN += e;
    a0 = fmaf(e, bf16lo_f32(kv.y), a0);
    a1 = fmaf(e, bf16hi_f32(kv.y), a1);
    a2 = fmaf(e, bf16lo_f32(kv.w), a2);
    a3 = fmaf(e, bf16hi_f32(kv.w), a3);
}

__global__ __launch_bounds__(256) void aggregate_kernel(
    const int* __restrict__ pvec, const int* __restrict__ sc,
    const float* __restrict__ Q, const unsigned int* __restrict__ KVP,
    float* __restrict__ out, int N) {
    const int t = blockIdx.x * 256 + threadIdx.x;
    const int n = t >> 6;
    const int l = t & 63;
    if (n >= N) return;
    const int d  = l & 15;              // dim quad
    const int es = l >> 4;              // edge slot 0..3

    int w = 0;
    if (l < 48) w = pvec[(size_t)n * 48 + l];   // one coalesced record load
    const float4 q4 = *(const float4*)(Q + (size_t)n * 64 + 4 * d);
    const int deg = __shfl(w, 0);

    float aN = 0.f, a0 = 0.f, a1 = 0.f, a2 = 0.f, a3 = 0.f;

    if (deg > 0) {
        const int cnt0 = min(deg, PADC);
        const int nst = (cnt0 + 3) >> 2;
        int si = 0;
        // Quad ladder (only last step can be partial).
        for (; si + 4 <= nst; si += 4) {
            const int e0 = si * 4 + es;
            const bool ok3 = e0 + 12 < cnt0;
            const int c0 = __shfl(w, 2 + e0);
            const int c1 = __shfl(w, 2 + e0 + 4);
            const int c2 = __shfl(w, 2 + e0 + 8);
            const int c3 = __shfl(w, ok3 ? 2 + e0 + 12 : 2);
            const uint4 kv0 = *(const uint4*)(KVP + (size_t)c0 * 64 + 4 * d);
            const uint4 kv1 = *(const uint4*)(KVP + (size_t)c1 * 64 + 4 * d);
            const uint4 kv2 = *(const uint4*)(KVP + (size_t)c2 * 64 + 4 * d);
            const uint4 kv3 = *(const uint4*)(KVP + (size_t)c3 * 64 + 4 * d);
            agg_step(kv0, q4, true, aN, a0, a1, a2, a3);
            agg_step(kv1, q4, true, aN, a0, a1, a2, a3);
            agg_step(kv2, q4, true, aN, a0, a1, a2, a3);
            agg_step(kv3, q4, ok3, aN, a0, a1, a2, a3);
        }
        // Pair ladder.
        if (si + 2 <= nst) {
            const int e0 = si * 4 + es;
            const bool ok1 = e0 + 4 < cnt0;
            const int c0 = __shfl(w, 2 + e0);
            const int c1 = __shfl(w, ok1 ? 2 + e0 + 4 : 2);
            const uint4 kv0 = *(const uint4*)(KVP + (size_t)c0 * 64 + 4 * d);
            const uint4 kv1 = *(const uint4*)(KVP + (size_t)c1 * 64 + 4 * d);
            agg_step(kv0, q4, true, aN, a0, a1, a2, a3);
            agg_step(kv1, q4, ok1, aN, a0, a1, a2, a3);
            si += 2;
        }
        // Single (possibly partial) step.
        if (si < nst) {
            const int e0 = si * 4 + es;
            const bool ok0 = e0 < cnt0;
            const int c0 = __shfl(w, ok0 ? 2 + e0 : 2);
            const uint4 kv0 = *(const uint4*)(KVP + (size_t)c0 * 64 + 4 * d);
            agg_step(kv0, q4, ok0, aN, a0, a1, a2, a3);
        }
        // Rare tail: deg > PADC, read remaining edges from sc.
        if (deg > PADC) {
            const int off0 = __shfl(w, 1);
            for (int base = PADC; base < deg; base += 64) {
                const int cnt = min(64, deg - base);
                int myc = 0;
                if (l < cnt) myc = sc[off0 + base + l];
                const int nst2 = (cnt + 3) >> 2;
                int sj = 0;
                for (; sj + 4 <= nst2; sj += 4) {
                    const int e0 = sj * 4 + es;
                    const bool ok3 = e0 + 12 < cnt;
                    const int c0 = __shfl(myc, e0);
                    const int c1 = __shfl(myc, e0 + 4);
                    const int c2 = __shfl(myc, e0 + 8);
                    const int c3 = __shfl(myc, ok3 ? e0 + 12 : 0);
                    const uint4 kv0 = *(const uint4*)(KVP + (size_t)c0 * 64 + 4 * d);
                    const uint4 kv1 = *(const uint4*)(KVP + (size_t)c1 * 64 + 4 * d);
                    const uint4 kv2 = *(const uint4*)(KVP + (size_t)c2 * 64 + 4 * d);
                    const uint4 kv3 = *(const uint4*)(KVP + (size_t)c3 * 64 + 4 * d);
                    agg_step(kv0, q4, true, aN, a0, a1, a2, a3);
                    agg_step(kv1, q4, true, aN, a0, a1, a2, a3);
                    agg_step(kv2, q4, true, aN, a0, a1, a2, a3);
                    agg_step(kv3, q4, ok3, aN, a0, a1, a2, a3);
                }
                if (sj + 2 <= nst2) {
                    const int e0 = sj * 4 + es;
                    const bool ok1 = e0 + 4 < cnt;
                    const int c0 = __shfl(myc, e0);
                    const int c1 = __shfl(myc, ok1 ? e0 + 4 : 0);
                    const uint4 kv0 = *(const uint4*)(KVP + (size_t)c0 * 64 + 4 * d);
                    const uint4 kv1 = *(const uint4*)(KVP + (size_t)c1 * 64 + 4 * d);
                    agg_step(kv0, q4, true, aN, a0, a1, a2, a3);
                    agg_step(kv1, q4, ok1, aN, a0, a1, a2, a3);
                    sj += 2;
                }
                if (sj < nst2) {
                    const int e0 = sj * 4 + es;
                    const bool ok0 = e0 < cnt;
                    const int c0 = __shfl(myc, ok0 ? e0 : 0);
                    const uint4 kv0 = *(const uint4*)(KVP + (size_t)c0 * 64 + 4 * d);
                    agg_step(kv0, q4, ok0, aN, a0, a1, a2, a3);
                }
            }
        }
    }

    // Combine the four edge slots.
    aN += __shfl_xor(aN, 16);  aN += __shfl_xor(aN, 32);
    a0 += __shfl_xor(a0, 16);  a0 += __shfl_xor(a0, 32);
    a1 += __shfl_xor(a1, 16);  a1 += __shfl_xor(a1, 32);
    a2 += __shfl_xor(a2, 16);  a2 += __shfl_xor(a2, 32);
    a3 += __shfl_xor(a3, 16);  a3 += __shfl_xor(a3, 32);

    if (l < 16) {
        const float inv = 1.f / (aN + 1e-8f);
        float4 o;
        o.x = a0 * inv;
        o.y = a1 * inv;
        o.z = a2 * inv;
        o.w = a3 * inv;
        *(float4*)(out + (size_t)n * 64 + 4 * d) = o;
    }
}

extern "C" void kernel_launch(void* const* d_in, const int* in_sizes, int n_in,
                              void* d_out, int out_size, void* d_ws, size_t ws_size,
                              hipStream_t stream) {
    const float* emb = (const float*)d_in[0];
    const float* Wq  = (const float*)d_in[1];
    const float* Wk  = (const float*)d_in[2];
    const float* Wv  = (const float*)d_in[3];
    const int*   w32 = (const int*)d_in[4];

    const int N    = in_sizes[0] / D;   // 100000
    const int E    = in_sizes[4] / 2;   // 800000
    const int NB   = (N + 255) / 256;   // 391 buckets
    const int NBLK = (E + EB - 1) / EB; // 98 binning blocks
    const int QB   = (N + 255) / 256;   // 391 qkv blocks (256 nodes each)
    const size_t ND = (size_t)N * D;

    const int* rows = w32;            // validated r10: [2,E], rows = half 0
    const int* cols = w32 + E;

    // Workspace: WfH | WfL | Q f32 | KVP | pvec | sc | tmp | hist2d |
    // base2d | btot | bbase   (~77 MB)
    unsigned short* WfH = (unsigned short*)d_ws;           // 24 KB
    unsigned short* WfL = WfH + 12288;                     // 24 KB
    float*          Q   = (float*)(WfL + 12288);
    unsigned int*   KVP = (unsigned int*)(Q + ND);
    int*   pvec = (int*)(KVP + ND);   // N*48 ints (19.2 MB)
    int*   sc   = pvec + (size_t)N * 48;
    unsigned int* tmp = (unsigned int*)(sc + E);
    int*   hist2d = (int*)(tmp + E);  // NBLK*NB
    int*   base2d = hist2d + NBLK * NB;
    int*   btot   = base2d + NBLK * NB;
    int*   bbase  = btot + NB;

    float* out = (float*)d_out;

    // 0) W -> hi/lo MFMA fragment order
    prep_w_kernel<<<48, 256, 0, stream>>>(Wq, Wk, Wv, WfH, WfL);

    // 1) fused: bin_hist (blocks [0,NBLK)) + QKV (blocks [NBLK,NBLK+QB))
    fused_qkv_hist_kernel<<<NBLK + QB, 256, 0, stream>>>(
        emb, WfH, WfL, N, Q, KVP, rows, hist2d, E, NB, NBLK);

    // 2) per-bucket scans + private scatter + bucket sort (writes pvec, sc)
    scan2d_kernel<<<NB, 256, 0, stream>>>(hist2d, base2d, btot, NBLK, NB);
    bscan_kernel<<<1, 256, 0, stream>>>(btot, bbase, NB);
    scatter2d_kernel<<<NBLK, 256, 0, stream>>>(rows, cols, base2d, bbase,
                                               tmp, E, NB);
    bucket_sort_kernel<<<NB, 256, 0, stream>>>(tmp, bbase, btot, pvec, sc,
                                               N, E, NB);

    // 3) Atomic-free aggregation: one wave per node, 2-hop serial chain
    aggregate_kernel<<<((size_t)N * 64 + 255) / 256, 256, 0, stream>>>(
        pvec, sc, Q, KVP, out, N);
}